// Round 4
// baseline (398.333 us; speedup 1.0000x reference)
//
#include <hip/hip_runtime.h>
#include <math.h>

// Problem constants
//   B*S = 8192 tokens, K=8 selected neurons, N_BASIS=32, RANK=8
//   D_MODEL=256 (16x16), hidden 64 (8x8), D_HID=1024 (32x32)
// Workspace layout (floats): wr[8192][32] | h[8192][64] | g[8192][1024]  (~36.7 MB)

__device__ __forceinline__ float gelu_exact(float v) {
    return 0.5f * v * (1.0f + erff(v * 0.70710678118654752440f));
}

// ---------------- K1: routing -> wr[token][32] ----------------
__global__ __launch_bounds__(64) void k_route(
    const int* __restrict__ nidx, const float* __restrict__ nw,
    const float* __restrict__ recipes, float* __restrict__ wr_out)
{
    const int t = blockIdx.x * 64 + threadIdx.x;   // 8192 tokens
    float acc[32];
#pragma unroll
    for (int n = 0; n < 32; n++) acc[n] = 0.f;
#pragma unroll
    for (int k = 0; k < 8; k++) {
        const int   id = nidx[t * 8 + k];
        const float wk = nw[t * 8 + k];
        const float4* row = (const float4*)(recipes + id * 32);
        float v[32];
#pragma unroll
        for (int q = 0; q < 8; q++) {
            float4 f = row[q];
            v[q*4+0] = f.x; v[q*4+1] = f.y; v[q*4+2] = f.z; v[q*4+3] = f.w;
        }
        float m = v[0];
#pragma unroll
        for (int n = 1; n < 32; n++) m = fmaxf(m, v[n]);
        float s = 0.f;
#pragma unroll
        for (int n = 0; n < 32; n++) { float e = expf(v[n] - m); v[n] = e; s += e; }
        const float iv = wk / s;
#pragma unroll
        for (int n = 0; n < 32; n++) acc[n] += v[n] * iv;
    }
    float4* o = (float4*)(wr_out + t * 32);
#pragma unroll
    for (int q = 0; q < 8; q++)
        o[q] = make_float4(acc[q*4+0], acc[q*4+1], acc[q*4+2], acc[q*4+3]);
}

// ---------------- K2: stage A  x[256] -> h[64], 8 tokens/block ----------------
__global__ __launch_bounds__(512) void k_stageA(
    const float* __restrict__ x, const float* __restrict__ wr,
    const float* __restrict__ A1, const float* __restrict__ A2,
    float* __restrict__ h_out)
{
    __shared__ float ca[8 * 1024];      // cores (cA1 then cA2), [t][1024]
    __shared__ float tl[8 * 1088];      // temp  [t][j(16)][68]
    const int tid = threadIdx.x;
    const int t0  = blockIdx.x * 8;

    // ---- build cA1: thread owns e2 = tid*2 for all 8 tokens (wr via uniform/scalar loads)
    {
        const int e2 = tid * 2;
        float2 c[8];
#pragma unroll
        for (int tt = 0; tt < 8; tt++) c[tt] = make_float2(0.f, 0.f);
#pragma unroll 4
        for (int n = 0; n < 32; n++) {
            const float2 a = *(const float2*)(A1 + n * 1024 + e2);
#pragma unroll
            for (int tt = 0; tt < 8; tt++) {
                const float s = wr[(t0 + tt) * 32 + n];   // uniform -> s_load
                c[tt].x += s * a.x; c[tt].y += s * a.y;
            }
        }
#pragma unroll
        for (int tt = 0; tt < 8; tt++) *(float2*)(ca + tt * 1024 + e2) = c[tt];
    }
    __syncthreads();

    // ---- temp build: thread (t = tid>>6, j = (tid&63)>>2, eh = tid&3) ----
    {
        const int t = tid >> 6, g = tid & 63, j = g >> 2, eh = g & 3;
        float xr[16];
#pragma unroll
        for (int i = 0; i < 16; i++) xr[i] = x[(t0 + t) * 256 + i * 16 + j];
        float tr[16];
#pragma unroll
        for (int q = 0; q < 16; q++) tr[q] = 0.f;
#pragma unroll
        for (int i = 0; i < 16; i++) {
            const float xv = xr[i];
#pragma unroll
            for (int q = 0; q < 4; q++) {
                const float4 cv = *(const float4*)(ca + t * 1024 + i * 64 + eh * 16 + q * 4);
                tr[q*4+0] += xv * cv.x; tr[q*4+1] += xv * cv.y;
                tr[q*4+2] += xv * cv.z; tr[q*4+3] += xv * cv.w;
            }
        }
#pragma unroll
        for (int q = 0; q < 4; q++)
            *(float4*)(tl + t * 1088 + j * 68 + eh * 16 + q * 4) =
                make_float4(tr[q*4+0], tr[q*4+1], tr[q*4+2], tr[q*4+3]);
    }
    __syncthreads();

    // ---- build cA2 into ca (overwrite) ----
    {
        const int e2 = tid * 2;
        float2 c[8];
#pragma unroll
        for (int tt = 0; tt < 8; tt++) c[tt] = make_float2(0.f, 0.f);
#pragma unroll 4
        for (int n = 0; n < 32; n++) {
            const float2 a = *(const float2*)(A2 + n * 1024 + e2);
#pragma unroll
            for (int tt = 0; tt < 8; tt++) {
                const float s = wr[(t0 + tt) * 32 + n];
                c[tt].x += s * a.x; c[tt].y += s * a.y;
            }
        }
#pragma unroll
        for (int tt = 0; tt < 8; tt++) *(float2*)(ca + tt * 1024 + e2) = c[tt];
    }
    __syncthreads();

    // ---- h: thread (t, k = (tid&63)>>3, l = tid&7) ----
    {
        const int t = tid >> 6, g = tid & 63, k = g >> 3, l = g & 7;
        float acc = 0.f;
#pragma unroll
        for (int j = 0; j < 16; j++) {
#pragma unroll
            for (int r = 0; r < 8; r++) {
                acc += tl[t * 1088 + j * 68 + r * 8 + k] *
                       ca[t * 1024 + r * 128 + j * 8 + l];
            }
        }
        h_out[(t0 + t) * 64 + g] = acc;
    }
}

// ---------------- K3: stage B  h[64] -> g[1024]=gelu(out), 8 tokens/block ----------------
__global__ __launch_bounds__(512) void k_stageB(
    const float* __restrict__ hin, const float* __restrict__ wr,
    const float* __restrict__ B1, const float* __restrict__ B2,
    float* __restrict__ g_out)
{
    __shared__ float hs [8 * 64];     // [t][64]
    __shared__ float cb1[8 * 520];    // [t][rr*256 + i*32 + k]
    __shared__ float cb2[8 * 520];    // [t][rr*256 + j*32 + l]
    __shared__ float t2 [8 * 520];    // [t][rr*256 + j*32 + k]
    const int tid = threadIdx.x;
    const int t0  = blockIdx.x * 8;

    hs[tid] = hin[t0 * 64 + tid];

    // ---- build mapping ----
    const int tg_v = tid >> 8;                              // 0..1, wave-uniform
    const int tg   = __builtin_amdgcn_readfirstlane(tg_v);  // force SGPR -> s_load of wr
    const int pos  = tid & 255;
    const int b    = pos >> 7;         // 0: B1->cb1, 1: B2->cb2
    const int rr   = (pos >> 6) & 1;   // r within pair
    const int q    = pos & 63;         // float4 index within 256-float slice
    const float* bankp = b ? B2 : B1;
    const int    rstr  = b ? 256 : 32;
    const int    off0  = b ? (q * 4) : ((q >> 3) * 256 + (q & 7) * 4);
    float* ldst = (b ? cb2 : cb1) + rr * 256 + q * 4 + tg * 4 * 520;
    const float* wrp = wr + (t0 + tg * 4) * 32;             // 4 tokens, stride 32

    // ---- consume mappings ----
    const int tw = tid >> 6;                         // wave id = token
    const int g2 = tid & 63, j2 = g2 >> 3, k42 = g2 & 7;          // P2
    const int k0 = (g2 & 7) * 4, l0 = (g2 >> 3) * 4;              // P3

    float o[4][4];
#pragma unroll
    for (int a = 0; a < 4; a++)
#pragma unroll
        for (int li = 0; li < 4; li++) o[a][li] = 0.f;

    for (int rp = 0; rp < 4; rp++) {
        // ---- P1: build cb1/cb2 for r-pair; distinct-lane coalesced loads ----
        {
            const float* p = bankp + off0 + (rp * 2 + rr) * rstr;
            float4 a0 = make_float4(0.f,0.f,0.f,0.f), a1 = a0, a2 = a0, a3 = a0;
#pragma unroll 4
            for (int n = 0; n < 32; n++) {
                const float4 bv = *(const float4*)(p + n * 2048);
                const float s0 = wrp[0 * 32 + n];
                const float s1 = wrp[1 * 32 + n];
                const float s2 = wrp[2 * 32 + n];
                const float s3 = wrp[3 * 32 + n];
                a0.x += s0 * bv.x; a0.y += s0 * bv.y; a0.z += s0 * bv.z; a0.w += s0 * bv.w;
                a1.x += s1 * bv.x; a1.y += s1 * bv.y; a1.z += s1 * bv.z; a1.w += s1 * bv.w;
                a2.x += s2 * bv.x; a2.y += s2 * bv.y; a2.z += s2 * bv.z; a2.w += s2 * bv.w;
                a3.x += s3 * bv.x; a3.y += s3 * bv.y; a3.z += s3 * bv.z; a3.w += s3 * bv.w;
            }
            *(float4*)(ldst + 0 * 520) = a0;
            *(float4*)(ldst + 1 * 520) = a1;
            *(float4*)(ldst + 2 * 520) = a2;
            *(float4*)(ldst + 3 * 520) = a3;
        }
        __syncthreads();

        // ---- P2: t2[t][rr][j][k] = sum_i hs[t][i*8+j] * cb1[t][rr][i][k] ----
        {
#pragma unroll
            for (int r2 = 0; r2 < 2; r2++) {
                float4 acc = make_float4(0.f, 0.f, 0.f, 0.f);
#pragma unroll
                for (int i = 0; i < 8; i++) {
                    const float  hv = hs[tw * 64 + i * 8 + j2];
                    const float4 cv = *(const float4*)(cb1 + tw * 520 + r2 * 256 + i * 32 + k42 * 4);
                    acc.x += hv * cv.x; acc.y += hv * cv.y;
                    acc.z += hv * cv.z; acc.w += hv * cv.w;
                }
                *(float4*)(t2 + tw * 520 + r2 * 256 + j2 * 32 + k42 * 4) = acc;
            }
        }
        __syncthreads();

        // ---- P3: o[a][li] += sum_{rr,j} t2[t][rr][j][k0+a] * cb2[t][rr][j][l0+li] ----
        {
#pragma unroll
            for (int r2 = 0; r2 < 2; r2++) {
#pragma unroll
                for (int j = 0; j < 8; j++) {
                    const float4 tv4 = *(const float4*)(t2  + tw * 520 + r2 * 256 + j * 32 + k0);
                    const float4 cv4 = *(const float4*)(cb2 + tw * 520 + r2 * 256 + j * 32 + l0);
                    const float tv[4] = {tv4.x, tv4.y, tv4.z, tv4.w};
                    const float cv[4] = {cv4.x, cv4.y, cv4.z, cv4.w};
#pragma unroll
                    for (int a = 0; a < 4; a++)
#pragma unroll
                        for (int li = 0; li < 4; li++)
                            o[a][li] += tv[a] * cv[li];
                }
            }
        }
        __syncthreads();   // before next r-pair build overwrites cb1/cb2/t2
    }

    // ---- gelu + store ----
    const int tok = t0 + tw;
#pragma unroll
    for (int a = 0; a < 4; a++) {
        float4 vg;
        vg.x = gelu_exact(o[a][0]); vg.y = gelu_exact(o[a][1]);
        vg.z = gelu_exact(o[a][2]); vg.w = gelu_exact(o[a][3]);
        *(float4*)(g_out + tok * 1024 + (k0 + a) * 32 + l0) = vg;
    }
}

// ---------------- K4: down-proj  y = g[8192x1024] @ W[1024x256] + b ----------------
// Broadcast-W design: block 256 thr = 4 waves; wave (kh = w>>1, nh = w&1).
// Tile m64 (lane = m) x n64 (nh picks 32-col slice); K=1024 split in halves per kh.
// W[k][nb..nb+31] is wave-uniform -> SGPR s_loads (no LDS, no per-lane VMEM).
// g staged global->reg->LDS double-buffered, transposed [kk][m] pad 68.
// Grid 512 blocks (2/CU). Block-internal K-reduction via LDS at end.
__global__ __launch_bounds__(256, 2) void k_down(
    const float* __restrict__ g, const float* __restrict__ W,
    const float* __restrict__ bias, float* __restrict__ y)
{
    __shared__ float gT[2][2][32][68];   // [buf][kh][kk][m] 34.8 KB
    __shared__ float px[2][64][36];      // [nh][m][32] exchange, 18.4 KB
    const int tid  = threadIdx.x;
    const int lane = tid & 63;                                // = m within tile
    const int wvu  = __builtin_amdgcn_readfirstlane(tid >> 6);
    const int kh   = wvu >> 1;
    const int nh   = wvu & 1;
    const int m0   = (blockIdx.x >> 2) * 64;
    const int n0   = (blockIdx.x & 3) * 64;
    const int nb   = n0 + nh * 32;

    // staging: threads 0-127 stage kh0 tile, 128-255 kh1 tile; 16 floats each
    const int sh   = tid >> 7;
    const int sidx = tid & 127;
    const int sm   = sidx >> 2;          // rows sm and sm+32
    const int sk   = (sidx & 3) * 8;     // k-offset (two float4)
    const float* gs = g + (m0 + sm) * 1024 + sh * 512 + sk;

    float acc[32];
#pragma unroll
    for (int q = 0; q < 32; q++) acc[q] = 0.f;

    float4 r0, r1, r2, r3;
#define LOADG(IT) { const float* p_ = gs + (IT) * 32;                          \
    r0 = *(const float4*)(p_);         r1 = *(const float4*)(p_ + 4);          \
    r2 = *(const float4*)(p_ + 32768); r3 = *(const float4*)(p_ + 32772); }
#define STOREG(BUF) { float* d_ = &gT[BUF][sh][0][0];                          \
    d_[(sk+0)*68+sm]=r0.x; d_[(sk+1)*68+sm]=r0.y;                              \
    d_[(sk+2)*68+sm]=r0.z; d_[(sk+3)*68+sm]=r0.w;                              \
    d_[(sk+4)*68+sm]=r1.x; d_[(sk+5)*68+sm]=r1.y;                              \
    d_[(sk+6)*68+sm]=r1.z; d_[(sk+7)*68+sm]=r1.w;                              \
    d_[(sk+0)*68+sm+32]=r2.x; d_[(sk+1)*68+sm+32]=r2.y;                        \
    d_[(sk+2)*68+sm+32]=r2.z; d_[(sk+3)*68+sm+32]=r2.w;                        \
    d_[(sk+4)*68+sm+32]=r3.x; d_[(sk+5)*68+sm+32]=r3.y;                        \
    d_[(sk+6)*68+sm+32]=r3.z; d_[(sk+7)*68+sm+32]=r3.w; }

    LOADG(0); STOREG(0);
    __syncthreads();
    int buf = 0;
#pragma unroll 1
    for (int it = 0; it < 16; it++) {
        if (it < 15) LOADG(it + 1);               // issue-early (hide under compute)
        const float* gTb = &gT[buf][kh][0][0];
        const int kb = kh * 512 + it * 32;
#pragma unroll
        for (int kk = 0; kk < 32; kk++) {
            const float gv = gTb[kk * 68 + lane];
            const float* Wrow = W + (kb + kk) * 256 + nb;   // wave-uniform -> s_load
            const float4 w0 = *(const float4*)(Wrow +  0);
            const float4 w1 = *(const float4*)(Wrow +  4);
            const float4 w2 = *(const float4*)(Wrow +  8);
            const float4 w3 = *(const float4*)(Wrow + 12);
            const float4 w4 = *(const float4*)(Wrow + 16);
            const float4 w5 = *(const float4*)(Wrow + 20);
            const float4 w6 = *(const float4*)(Wrow + 24);
            const float4 w7 = *(const float4*)(Wrow + 28);
            acc[ 0] += gv*w0.x; acc[ 1] += gv*w0.y; acc[ 2] += gv*w0.z; acc[ 3] += gv*w0.w;
            acc[ 4] += gv*w1.x; acc[ 5] += gv*w1.y; acc[ 6] += gv*w1.z; acc[ 7] += gv*w1.w;
            acc[ 8] += gv*w2.x; acc[ 9] += gv*w2.y; acc[10] += gv*w2.z; acc[11] += gv*w2.w;
            acc[12] += gv*w3.x; acc[13] += gv*w3.y; acc[14] += gv*w3.z; acc[15] += gv*w3.w;
            acc[16] += gv*w4.x; acc[17] += gv*w4.y; acc[18] += gv*w4.z; acc[19] += gv*w4.w;
            acc[20] += gv*w5.x; acc[21] += gv*w5.y; acc[22] += gv*w5.z; acc[23] += gv*w5.w;
            acc[24] += gv*w6.x; acc[25] += gv*w6.y; acc[26] += gv*w6.z; acc[27] += gv*w6.w;
            acc[28] += gv*w7.x; acc[29] += gv*w7.y; acc[30] += gv*w7.z; acc[31] += gv*w7.w;
        }
        if (it < 15) STOREG(buf ^ 1);             // write-late (other buffer, no hazard)
        __syncthreads();
        buf ^= 1;
    }
#undef LOADG
#undef STOREG

    // ---- block-internal K reduction + bias + store ----
    if (kh == 1) {
#pragma unroll
        for (int q = 0; q < 8; q++)
            *(float4*)(&px[nh][lane][q * 4]) =
                make_float4(acc[q*4+0], acc[q*4+1], acc[q*4+2], acc[q*4+3]);
    }
    __syncthreads();
    if (kh == 0) {
        float* yr = y + (m0 + lane) * 256 + nb;
#pragma unroll
        for (int q = 0; q < 8; q++) {
            const float4 pv = *(const float4*)(&px[nh][lane][q * 4]);
            const float4 bv = *(const float4*)(bias + nb + q * 4);
            *(float4*)(yr + q * 4) = make_float4(acc[q*4+0] + pv.x + bv.x,
                                                 acc[q*4+1] + pv.y + bv.y,
                                                 acc[q*4+2] + pv.z + bv.z,
                                                 acc[q*4+3] + pv.w + bv.w);
        }
    }
}

extern "C" void kernel_launch(void* const* d_in, const int* in_sizes, int n_in,
                              void* d_out, int out_size, void* d_ws, size_t ws_size,
                              hipStream_t stream)
{
    const float* x    = (const float*)d_in[0];
    const int*   nidx = (const int*)  d_in[1];
    const float* nw   = (const float*)d_in[2];
    const float* rec  = (const float*)d_in[3];
    const float* A1   = (const float*)d_in[4];
    const float* A2   = (const float*)d_in[5];
    const float* B1   = (const float*)d_in[6];
    const float* B2   = (const float*)d_in[7];
    const float* Wd   = (const float*)d_in[8];
    const float* bd   = (const float*)d_in[9];
    float* y  = (float*)d_out;

    float* wr = (float*)d_ws;                 // 8192*32
    float* h  = wr + 8192 * 32;               // 8192*64
    float* g  = h  + 8192 * 64;               // 8192*1024   (total ~36.7 MB of ws)

    k_route <<<128,  64, 0, stream>>>(nidx, nw, rec, wr);
    k_stageA<<<1024, 512, 0, stream>>>(x, wr, A1, A2, h);
    k_stageB<<<1024, 512, 0, stream>>>(h, wr, B1, B2, g);
    k_down  <<<512,  256, 0, stream>>>(g, Wd, bd, y);
}

// Round 5
// 134.727 us; speedup vs baseline: 2.9566x; 2.9566x over previous
//
#include <hip/hip_runtime.h>
#include <math.h>

// B*S = 8192 tokens, K=8, N_BASIS=32, RANK=8, D_MODEL=256, D_HID=1024
// ws layout: wr[8192][32] f32 (1MB) | h[8192][64] f32 (2MB, later reused for Wth/Wtl bf16)
//            | gh[8192][1024] bf16 (16MB) | gl[8192][1024] bf16 (16MB)   total 36.56 MB

typedef unsigned short u16;
typedef __attribute__((ext_vector_type(8))) __bf16 bf16x8;
typedef __attribute__((ext_vector_type(4))) float f32x4;
union ABCast { float4 f; bf16x8 v; };
union BFBits { __bf16 b; u16 u; };

__device__ __forceinline__ float gelu_exact(float v) {
    return 0.5f * v * (1.0f + erff(v * 0.70710678118654752440f));
}
__device__ __forceinline__ u16 f2bf_bits(float f) {
    BFBits c; c.b = (__bf16)f; return c.u;
}
__device__ __forceinline__ float bfbits2f(u16 u) {
    BFBits c; c.u = u; return (float)c.b;
}

// ---------------- K1: routing -> wr[token][32] ----------------
__global__ __launch_bounds__(64) void k_route(
    const int* __restrict__ nidx, const float* __restrict__ nw,
    const float* __restrict__ recipes, float* __restrict__ wr_out)
{
    const int t = blockIdx.x * 64 + threadIdx.x;
    float acc[32];
#pragma unroll
    for (int n = 0; n < 32; n++) acc[n] = 0.f;
#pragma unroll
    for (int k = 0; k < 8; k++) {
        const int   id = nidx[t * 8 + k];
        const float wk = nw[t * 8 + k];
        const float4* row = (const float4*)(recipes + id * 32);
        float v[32];
#pragma unroll
        for (int q = 0; q < 8; q++) {
            float4 f = row[q];
            v[q*4+0] = f.x; v[q*4+1] = f.y; v[q*4+2] = f.z; v[q*4+3] = f.w;
        }
        float m = v[0];
#pragma unroll
        for (int n = 1; n < 32; n++) m = fmaxf(m, v[n]);
        float s = 0.f;
#pragma unroll
        for (int n = 0; n < 32; n++) { float e = expf(v[n] - m); v[n] = e; s += e; }
        const float iv = wk / s;
#pragma unroll
        for (int n = 0; n < 32; n++) acc[n] += v[n] * iv;
    }
    float4* o = (float4*)(wr_out + t * 32);
#pragma unroll
    for (int q = 0; q < 8; q++)
        o[q] = make_float4(acc[q*4+0], acc[q*4+1], acc[q*4+2], acc[q*4+3]);
}

// ---------------- K2: stage A  x[256] -> h[64], 8 tokens/block ----------------
__global__ __launch_bounds__(512) void k_stageA(
    const float* __restrict__ x, const float* __restrict__ wr,
    const float* __restrict__ A1, const float* __restrict__ A2,
    float* __restrict__ h_out)
{
    __shared__ float ca[8 * 1024];
    __shared__ float tl[8 * 1088];
    const int tid = threadIdx.x;
    const int t0  = blockIdx.x * 8;

    {   // build cA1
        const int e2 = tid * 2;
        float2 c[8];
#pragma unroll
        for (int tt = 0; tt < 8; tt++) c[tt] = make_float2(0.f, 0.f);
#pragma unroll 4
        for (int n = 0; n < 32; n++) {
            const float2 a = *(const float2*)(A1 + n * 1024 + e2);
#pragma unroll
            for (int tt = 0; tt < 8; tt++) {
                const float s = wr[(t0 + tt) * 32 + n];
                c[tt].x += s * a.x; c[tt].y += s * a.y;
            }
        }
#pragma unroll
        for (int tt = 0; tt < 8; tt++) *(float2*)(ca + tt * 1024 + e2) = c[tt];
    }
    __syncthreads();
    {   // temp = x_fold . cA1
        const int t = tid >> 6, g = tid & 63, j = g >> 2, eh = g & 3;
        float xr[16];
#pragma unroll
        for (int i = 0; i < 16; i++) xr[i] = x[(t0 + t) * 256 + i * 16 + j];
        float tr[16];
#pragma unroll
        for (int q = 0; q < 16; q++) tr[q] = 0.f;
#pragma unroll
        for (int i = 0; i < 16; i++) {
            const float xv = xr[i];
#pragma unroll
            for (int q = 0; q < 4; q++) {
                const float4 cv = *(const float4*)(ca + t * 1024 + i * 64 + eh * 16 + q * 4);
                tr[q*4+0] += xv * cv.x; tr[q*4+1] += xv * cv.y;
                tr[q*4+2] += xv * cv.z; tr[q*4+3] += xv * cv.w;
            }
        }
#pragma unroll
        for (int q = 0; q < 4; q++)
            *(float4*)(tl + t * 1088 + j * 68 + eh * 16 + q * 4) =
                make_float4(tr[q*4+0], tr[q*4+1], tr[q*4+2], tr[q*4+3]);
    }
    __syncthreads();
    {   // build cA2
        const int e2 = tid * 2;
        float2 c[8];
#pragma unroll
        for (int tt = 0; tt < 8; tt++) c[tt] = make_float2(0.f, 0.f);
#pragma unroll 4
        for (int n = 0; n < 32; n++) {
            const float2 a = *(const float2*)(A2 + n * 1024 + e2);
#pragma unroll
            for (int tt = 0; tt < 8; tt++) {
                const float s = wr[(t0 + tt) * 32 + n];
                c[tt].x += s * a.x; c[tt].y += s * a.y;
            }
        }
#pragma unroll
        for (int tt = 0; tt < 8; tt++) *(float2*)(ca + tt * 1024 + e2) = c[tt];
    }
    __syncthreads();
    {   // h = temp . cA2
        const int t = tid >> 6, g = tid & 63, k = g >> 3, l = g & 7;
        float acc = 0.f;
#pragma unroll
        for (int j = 0; j < 16; j++) {
#pragma unroll
            for (int r = 0; r < 8; r++) {
                acc += tl[t * 1088 + j * 68 + r * 8 + k] *
                       ca[t * 1024 + r * 128 + j * 8 + l];
            }
        }
        h_out[(t0 + t) * 64 + g] = acc;
    }
}

// ---------------- K3: stage B  h[64] -> gh/gl bf16 split of gelu(out) ----------------
__global__ __launch_bounds__(512) void k_stageB(
    const float* __restrict__ hin, const float* __restrict__ wr,
    const float* __restrict__ B1, const float* __restrict__ B2,
    u16* __restrict__ ghp, u16* __restrict__ glp)
{
    __shared__ float hs [8 * 64];
    __shared__ float cb1[8 * 520];
    __shared__ float cb2[8 * 520];
    __shared__ float t2 [8 * 520];
    const int tid = threadIdx.x;
    const int t0  = blockIdx.x * 8;

    hs[tid] = hin[t0 * 64 + tid];

    const int tg_v = tid >> 8;
    const int tg   = __builtin_amdgcn_readfirstlane(tg_v);
    const int pos  = tid & 255;
    const int b    = pos >> 7;
    const int rr   = (pos >> 6) & 1;
    const int q    = pos & 63;
    const float* bankp = b ? B2 : B1;
    const int    rstr  = b ? 256 : 32;
    const int    off0  = b ? (q * 4) : ((q >> 3) * 256 + (q & 7) * 4);
    float* ldst = (b ? cb2 : cb1) + rr * 256 + q * 4 + tg * 4 * 520;
    const float* wrp = wr + (t0 + tg * 4) * 32;

    const int tw = tid >> 6;
    const int g2 = tid & 63, j2 = g2 >> 3, k42 = g2 & 7;
    const int k0 = (g2 & 7) * 4, l0 = (g2 >> 3) * 4;

    float o[4][4];
#pragma unroll
    for (int a = 0; a < 4; a++)
#pragma unroll
        for (int li = 0; li < 4; li++) o[a][li] = 0.f;

    for (int rp = 0; rp < 4; rp++) {
        {   // P1 build cb1/cb2 (distinct-lane coalesced)
            const float* p = bankp + off0 + (rp * 2 + rr) * rstr;
            float4 a0 = make_float4(0.f,0.f,0.f,0.f), a1 = a0, a2 = a0, a3 = a0;
#pragma unroll 4
            for (int n = 0; n < 32; n++) {
                const float4 bv = *(const float4*)(p + n * 2048);
                const float s0 = wrp[0 * 32 + n];
                const float s1 = wrp[1 * 32 + n];
                const float s2 = wrp[2 * 32 + n];
                const float s3 = wrp[3 * 32 + n];
                a0.x += s0 * bv.x; a0.y += s0 * bv.y; a0.z += s0 * bv.z; a0.w += s0 * bv.w;
                a1.x += s1 * bv.x; a1.y += s1 * bv.y; a1.z += s1 * bv.z; a1.w += s1 * bv.w;
                a2.x += s2 * bv.x; a2.y += s2 * bv.y; a2.z += s2 * bv.z; a2.w += s2 * bv.w;
                a3.x += s3 * bv.x; a3.y += s3 * bv.y; a3.z += s3 * bv.z; a3.w += s3 * bv.w;
            }
            *(float4*)(ldst + 0 * 520) = a0;
            *(float4*)(ldst + 1 * 520) = a1;
            *(float4*)(ldst + 2 * 520) = a2;
            *(float4*)(ldst + 3 * 520) = a3;
        }
        __syncthreads();
        {   // P2
#pragma unroll
            for (int r2 = 0; r2 < 2; r2++) {
                float4 acc = make_float4(0.f, 0.f, 0.f, 0.f);
#pragma unroll
                for (int i = 0; i < 8; i++) {
                    const float  hv = hs[tw * 64 + i * 8 + j2];
                    const float4 cv = *(const float4*)(cb1 + tw * 520 + r2 * 256 + i * 32 + k42 * 4);
                    acc.x += hv * cv.x; acc.y += hv * cv.y;
                    acc.z += hv * cv.z; acc.w += hv * cv.w;
                }
                *(float4*)(t2 + tw * 520 + r2 * 256 + j2 * 32 + k42 * 4) = acc;
            }
        }
        __syncthreads();
        {   // P3
#pragma unroll
            for (int r2 = 0; r2 < 2; r2++) {
#pragma unroll
                for (int j = 0; j < 8; j++) {
                    const float4 tv4 = *(const float4*)(t2  + tw * 520 + r2 * 256 + j * 32 + k0);
                    const float4 cv4 = *(const float4*)(cb2 + tw * 520 + r2 * 256 + j * 32 + l0);
                    const float tv[4] = {tv4.x, tv4.y, tv4.z, tv4.w};
                    const float cv[4] = {cv4.x, cv4.y, cv4.z, cv4.w};
#pragma unroll
                    for (int a = 0; a < 4; a++)
#pragma unroll
                        for (int li = 0; li < 4; li++)
                            o[a][li] += tv[a] * cv[li];
                }
            }
        }
        __syncthreads();
    }

    // gelu + bf16 split store (gh = bf16(v), gl = bf16(v - gh))
    const int tok = t0 + tw;
    u16* ghr = ghp + tok * 1024;
    u16* glr = glp + tok * 1024;
#pragma unroll
    for (int a = 0; a < 4; a++) {
        u16 hv[4], lv[4];
#pragma unroll
        for (int li = 0; li < 4; li++) {
            const float v = gelu_exact(o[a][li]);
            const u16 hb = f2bf_bits(v);
            hv[li] = hb;
            lv[li] = f2bf_bits(v - bfbits2f(hb));
        }
        *(ushort4*)(ghr + (k0 + a) * 32 + l0) = make_ushort4(hv[0], hv[1], hv[2], hv[3]);
        *(ushort4*)(glr + (k0 + a) * 32 + l0) = make_ushort4(lv[0], lv[1], lv[2], lv[3]);
    }
}

// ---------------- K3b: W split+transpose: W[1024][256] f32 -> Wth/Wtl[256][1024] bf16 ----------------
__global__ __launch_bounds__(256) void k_wsplit(
    const float* __restrict__ W, u16* __restrict__ wth, u16* __restrict__ wtl)
{
    __shared__ float lt[64 * 65];
    const int t  = threadIdx.x;
    const int k0 = (blockIdx.x >> 2) * 64;
    const int n0 = (blockIdx.x & 3) * 64;
    {   // load 64k x 64n tile (coalesced along n)
        const int kk = t >> 2, nf = (t & 3) * 16;
#pragma unroll
        for (int q = 0; q < 4; q++) {
            const float4 v = *(const float4*)(W + (k0 + kk) * 256 + n0 + nf + q * 4);
            lt[kk * 65 + nf + q*4+0] = v.x; lt[kk * 65 + nf + q*4+1] = v.y;
            lt[kk * 65 + nf + q*4+2] = v.z; lt[kk * 65 + nf + q*4+3] = v.w;
        }
    }
    __syncthreads();
    {   // write transposed (coalesced along k)
        const int nn = t >> 2, kf = (t & 3) * 16;
        union { u16 u[16]; float4 f4[2]; } uh, ul;
#pragma unroll
        for (int j = 0; j < 16; j++) {
            const float v = lt[(kf + j) * 65 + nn];
            const u16 hb = f2bf_bits(v);
            uh.u[j] = hb;
            ul.u[j] = f2bf_bits(v - bfbits2f(hb));
        }
        u16* dh = wth + (n0 + nn) * 1024 + k0 + kf;
        u16* dl = wtl + (n0 + nn) * 1024 + k0 + kf;
        *(float4*)(dh + 0) = uh.f4[0]; *(float4*)(dh + 8) = uh.f4[1];
        *(float4*)(dl + 0) = ul.f4[0]; *(float4*)(dl + 8) = ul.f4[1];
    }
}

// ---------------- K4: down-proj via MFMA bf16 3-pass split ----------------
// y[8192x256] = (gh+gl) @ (Wh+Wl)^ ~ gh@Wh + gh@Wl + gl@Wh  (+bias)
// Grid 256 = 128 m-tiles(64) x 2 n-tiles(128). Block 256 thr = 4 waves; wave w: n-slice 32.
// K-step 64; LDS in MFMA fragment order (lane-contiguous 16B); double-buffered.
// Frag layouts (16x16x32): A: lane holds row=l&15, k=8*(l>>4)+e ; B: col=l&15, k=8*(l>>4)+e.
__global__ __launch_bounds__(256) void k_down(
    const u16* __restrict__ ghp, const u16* __restrict__ glp,
    const u16* __restrict__ wthp, const u16* __restrict__ wtlp,
    const float* __restrict__ bias, float* __restrict__ y)
{
    // ushort units. A: [buf][hl2][ms4][kh2][lane64][e8] = 2*8192; B: [buf][hl2][ns8][kh2][lane64][e8] = 2*16384
    __shared__ __align__(16) u16 Ash[2][8192];
    __shared__ __align__(16) u16 Bsh[2][16384];
    const int tid  = threadIdx.x;
    const int lane = tid & 63;
    const int w    = tid >> 6;
    const int m0 = (blockIdx.x >> 1) * 64;
    const int bn = blockIdx.x & 1;

    // staging map: row = m (A) / n (B) within 16-subtile; cq = 8-elem chunk; sq = subtile
    const int row = tid & 15;
    const int cq  = (tid >> 4) & 3;
    const int sq  = tid >> 6;
    const int aGsrc  = (m0 + sq * 16 + row) * 1024 + cq * 8;
    const int bGsrc0 = (bn * 128 + sq * 16 + row) * 1024 + cq * 8;
    const int bGsrc1 = (bn * 128 + (sq + 4) * 16 + row) * 1024 + cq * 8;
    const int aDst  = sq * 2 * 512 + (cq * 16 + row) * 8;
    const int bDst0 = sq * 2 * 512 + (cq * 16 + row) * 8;
    const int bDst1 = (sq + 4) * 2 * 512 + (cq * 16 + row) * 8;

    f32x4 acc[4][2];
#pragma unroll
    for (int ms = 0; ms < 4; ms++)
#pragma unroll
        for (int ns = 0; ns < 2; ns++) acc[ms][ns] = (f32x4){0.f, 0.f, 0.f, 0.f};

    float4 rA0, rA1, rA2, rA3, rB0, rB1, rB2, rB3, rB4, rB5, rB6, rB7;
#define KD_LOAD(S) { const int ku = (S) * 64;                                   \
    rA0 = *(const float4*)(ghp  + aGsrc  + ku);                                 \
    rA1 = *(const float4*)(ghp  + aGsrc  + ku + 32);                            \
    rA2 = *(const float4*)(glp  + aGsrc  + ku);                                 \
    rA3 = *(const float4*)(glp  + aGsrc  + ku + 32);                            \
    rB0 = *(const float4*)(wthp + bGsrc0 + ku);                                 \
    rB1 = *(const float4*)(wthp + bGsrc0 + ku + 32);                            \
    rB2 = *(const float4*)(wthp + bGsrc1 + ku);                                 \
    rB3 = *(const float4*)(wthp + bGsrc1 + ku + 32);                            \
    rB4 = *(const float4*)(wtlp + bGsrc0 + ku);                                 \
    rB5 = *(const float4*)(wtlp + bGsrc0 + ku + 32);                            \
    rB6 = *(const float4*)(wtlp + bGsrc1 + ku);                                 \
    rB7 = *(const float4*)(wtlp + bGsrc1 + ku + 32); }
#define KD_WRITE(BF) { u16* A_ = &Ash[BF][0]; u16* B_ = &Bsh[BF][0];            \
    *(float4*)(A_ + aDst)         = rA0;  *(float4*)(A_ + aDst + 512)   = rA1;  \
    *(float4*)(A_ + aDst + 4096)  = rA2;  *(float4*)(A_ + aDst + 4608)  = rA3;  \
    *(float4*)(B_ + bDst0)        = rB0;  *(float4*)(B_ + bDst0 + 512)  = rB1;  \
    *(float4*)(B_ + bDst1)        = rB2;  *(float4*)(B_ + bDst1 + 512)  = rB3;  \
    *(float4*)(B_ + bDst0 + 8192) = rB4;  *(float4*)(B_ + bDst0 + 8704) = rB5;  \
    *(float4*)(B_ + bDst1 + 8192) = rB6;  *(float4*)(B_ + bDst1 + 8704) = rB7; }

    KD_LOAD(0); KD_WRITE(0);
    __syncthreads();

#pragma unroll 1
    for (int s = 0; s < 16; s++) {
        if (s < 15) KD_LOAD(s + 1);
        const u16* Ac = &Ash[s & 1][0];
        const u16* Bc = &Bsh[s & 1][0];
        ABCast tmp;
        bf16x8 bh_[2][2], bl_[2][2];
#pragma unroll
        for (int ns = 0; ns < 2; ns++)
#pragma unroll
            for (int kh = 0; kh < 2; kh++) {
                const int ofs = ((w * 2 + ns) * 2 + kh) * 512 + lane * 8;
                tmp.f = *(const float4*)(Bc + ofs);        bh_[ns][kh] = tmp.v;
                tmp.f = *(const float4*)(Bc + 8192 + ofs); bl_[ns][kh] = tmp.v;
            }
#pragma unroll
        for (int ms = 0; ms < 4; ms++) {
            bf16x8 ah0, ah1, al0, al1;
            tmp.f = *(const float4*)(Ac + (ms * 2 + 0) * 512 + lane * 8);        ah0 = tmp.v;
            tmp.f = *(const float4*)(Ac + (ms * 2 + 1) * 512 + lane * 8);        ah1 = tmp.v;
            tmp.f = *(const float4*)(Ac + 4096 + (ms * 2 + 0) * 512 + lane * 8); al0 = tmp.v;
            tmp.f = *(const float4*)(Ac + 4096 + (ms * 2 + 1) * 512 + lane * 8); al1 = tmp.v;
#pragma unroll
            for (int ns = 0; ns < 2; ns++) {
                acc[ms][ns] = __builtin_amdgcn_mfma_f32_16x16x32_bf16(ah0, bh_[ns][0], acc[ms][ns], 0, 0, 0);
                acc[ms][ns] = __builtin_amdgcn_mfma_f32_16x16x32_bf16(ah1, bh_[ns][1], acc[ms][ns], 0, 0, 0);
                acc[ms][ns] = __builtin_amdgcn_mfma_f32_16x16x32_bf16(ah0, bl_[ns][0], acc[ms][ns], 0, 0, 0);
                acc[ms][ns] = __builtin_amdgcn_mfma_f32_16x16x32_bf16(ah1, bl_[ns][1], acc[ms][ns], 0, 0, 0);
                acc[ms][ns] = __builtin_amdgcn_mfma_f32_16x16x32_bf16(al0, bh_[ns][0], acc[ms][ns], 0, 0, 0);
                acc[ms][ns] = __builtin_amdgcn_mfma_f32_16x16x32_bf16(al1, bh_[ns][1], acc[ms][ns], 0, 0, 0);
            }
        }
        if (s < 15) KD_WRITE((s + 1) & 1);
        __syncthreads();
    }
#undef KD_LOAD
#undef KD_WRITE

    // epilogue: C frag col=lane&15, row=(lane>>4)*4+reg
#pragma unroll
    for (int ns = 0; ns < 2; ns++) {
        const int n = bn * 128 + w * 32 + ns * 16 + (lane & 15);
        const float bv = bias[n];
#pragma unroll
        for (int ms = 0; ms < 4; ms++) {
            const int mb = m0 + ms * 16 + (lane >> 4) * 4;
#pragma unroll
            for (int r = 0; r < 4; r++)
                y[(mb + r) * 256 + n] = acc[ms][ns][r] + bv;
        }
    }
}

extern "C" void kernel_launch(void* const* d_in, const int* in_sizes, int n_in,
                              void* d_out, int out_size, void* d_ws, size_t ws_size,
                              hipStream_t stream)
{
    const float* x    = (const float*)d_in[0];
    const int*   nidx = (const int*)  d_in[1];
    const float* nw   = (const float*)d_in[2];
    const float* rec  = (const float*)d_in[3];
    const float* A1   = (const float*)d_in[4];
    const float* A2   = (const float*)d_in[5];
    const float* B1   = (const float*)d_in[6];
    const float* B2   = (const float*)d_in[7];
    const float* Wd   = (const float*)d_in[8];
    const float* bd   = (const float*)d_in[9];
    float* y  = (float*)d_out;

    float* wr = (float*)d_ws;                    // 1 MB
    float* h  = wr + 8192 * 32;                  // 2 MB
    u16*   gh = (u16*)(h + 8192 * 64);           // 16 MB bf16
    u16*   gl = gh + 8192 * 1024;                // 16 MB bf16
    u16*   wth = (u16*)h;                        // reuse h after k_stageB (0.5 MB)
    u16*   wtl = wth + 256 * 1024;               // 0.5 MB

    k_route <<<128,  64, 0, stream>>>(nidx, nw, rec, wr);
    k_stageA<<<1024, 512, 0, stream>>>(x, wr, A1, A2, h);
    k_stageB<<<1024, 512, 0, stream>>>(h, wr, B1, B2, gh, gl);
    k_wsplit<<<64,   256, 0, stream>>>(Wd, wth, wtl);
    k_down  <<<256,  256, 0, stream>>>(gh, gl, wth, wtl, bd, y);
}